// Round 7
// baseline (289.629 us; speedup 1.0000x reference)
//
#include <hip/hip_runtime.h>
#include <math.h>

// NoisyTopKRouter: B=4, T=4096, C=2048, E=64, K=8; rows = 16384.
// (1) convert_w: split w into hi/lo bf16 packed in MFMA-fragment order.
// (2) router_gemm: barrier-free hot loop. Block = 16 rows x 1024 k (K-split
//     x2). Whole x K-half staged pre-split into LDS once (1 barrier), then
//     32 MFMA iters with B frags direct from global (packed, coalesced,
//     L2-resident) -> f32 partials. 2 blocks/CU overlap stage vs compute.
// (3) router_epilogue: rank-by-counting top-8, sparse softmax, selective
//     f64 near-tie repair (verified rounds 4-6).

#define CDIM  2048
#define EDIM  64
#define NOUT  128
#define TOPK  8
#define NROWS 16384
#define BM    16             // rows per block
#define KHALF 1024
#define NKC   (KHALF / 32)   // 32 k-chunks of 32
#define TAU   1e-3f
#define XPITCH 2056          // shorts per row: hi[1024] | lo[1024] | pad[8]

typedef __attribute__((ext_vector_type(8))) short bf16x8;
typedef __attribute__((ext_vector_type(4))) float f32x4;

__device__ __forceinline__ void split8(const float4 a, const float4 b,
                                       bf16x8& h8, bf16x8& l8) {
    const float vv[8] = {a.x, a.y, a.z, a.w, b.x, b.y, b.z, b.w};
    #pragma unroll
    for (int j = 0; j < 8; ++j) {
        const __bf16 h = (__bf16)vv[j];
        const __bf16 l = (__bf16)(vv[j] - (float)h);
        h8[j] = __builtin_bit_cast(short, h);
        l8[j] = __builtin_bit_cast(short, l);
    }
}

// ---- kernel 1: pack w into MFMA-fragment order, hi/lo bf16.
// slot s = (kc*8 + cg)*64 + lane holds w[col = cg*16 + (lane&15)]
//                                    [k = kc*32 + (lane>>4)*8 + j]
__global__ __launch_bounds__(256)
void convert_w(const float* __restrict__ wr, const float* __restrict__ wn,
               short* __restrict__ whi, short* __restrict__ wlo) {
    const int s    = (int)blockIdx.x * 256 + (int)threadIdx.x;  // 0..32767
    const int lane = s & 63;
    const int cg   = (s >> 6) & 7;
    const int kc   = s >> 9;
    const int col  = cg * 16 + (lane & 15);
    const int k0   = kc * 32 + (lane >> 4) * 8;
    const float* src = (col < EDIM ? wr + (size_t)col * CDIM
                                   : wn + (size_t)(col - EDIM) * CDIM) + k0;
    const float4 a = *(const float4*)src;
    const float4 b = *(const float4*)(src + 4);
    bf16x8 h8, l8; split8(a, b, h8, l8);
    *(bf16x8*)(whi + (size_t)s * 8) = h8;
    *(bf16x8*)(wlo + (size_t)s * 8) = l8;
}

// ---- kernel 2: split-bf16 MFMA GEMM, stage-once / barrier-free loop
__global__ __launch_bounds__(256, 2)
void router_gemm(const float* __restrict__ x,
                 const short* __restrict__ whi,
                 const short* __restrict__ wlo,
                 float* __restrict__ part)
{
    __shared__ __align__(16) short xsh[BM][XPITCH];   // 64.25 KB

    const int tid  = (int)threadIdx.x;
    const int lane = tid & 63;
    const int wid  = tid >> 6;          // wave 0..3 -> cols wid*32..+31
    const int l15  = lane & 15;
    const int q    = lane >> 4;         // quad 0..3
    const int half = (int)blockIdx.x & 1;
    const int row0 = ((int)blockIdx.x >> 1) * BM;

    // ---- stage: 16 rows x 1024 k of x, split hi/lo, one barrier
    {
        const int r  = tid >> 4;          // 0..15
        const int kb = (tid & 15) * 8;    // 0..120
        const float* src = x + (size_t)(row0 + r) * CDIM + half * KHALF + kb;
        #pragma unroll
        for (int c = 0; c < 8; ++c) {
            const int k = kb + c * 128;
            const float4 a = *(const float4*)(src + c * 128);
            const float4 b = *(const float4*)(src + c * 128 + 4);
            bf16x8 h8, l8; split8(a, b, h8, l8);
            *(bf16x8*)&xsh[r][k]        = h8;
            *(bf16x8*)&xsh[r][1024 + k] = l8;
        }
    }
    __syncthreads();

    f32x4 acc[2];
    acc[0] = (f32x4){0.f, 0.f, 0.f, 0.f};
    acc[1] = (f32x4){0.f, 0.f, 0.f, 0.f};

    // ---- barrier-free MFMA loop: A from LDS, B direct from global (L2)
    const short* ar = &xsh[l15][q * 8];
    #pragma unroll 4
    for (int kc = 0; kc < NKC; ++kc) {
        const bf16x8 ah = *(const bf16x8*)(ar + kc * 32);
        const bf16x8 al = *(const bf16x8*)(ar + 1024 + kc * 32);
        const int base = (((half * NKC + kc) * 8 + wid * 2) * 64 + lane) * 8;
        #pragma unroll
        for (int c = 0; c < 2; ++c) {
            const bf16x8 bh = *(const bf16x8*)(whi + base + c * 512);
            const bf16x8 bl = *(const bf16x8*)(wlo + base + c * 512);
            acc[c] = __builtin_amdgcn_mfma_f32_16x16x32_bf16(ah, bh, acc[c], 0, 0, 0);
            acc[c] = __builtin_amdgcn_mfma_f32_16x16x32_bf16(al, bh, acc[c], 0, 0, 0);
            acc[c] = __builtin_amdgcn_mfma_f32_16x16x32_bf16(ah, bl, acc[c], 0, 0, 0);
        }
    }

    // ---- partial store (C/D: row = quad*4+reg, col = lane&15)
    float* dst = part + (size_t)half * NROWS * NOUT;
    #pragma unroll
    for (int c = 0; c < 2; ++c)
        #pragma unroll
        for (int g = 0; g < 4; ++g)
            dst[(size_t)(row0 + q * 4 + g) * NOUT + wid * 32 + c * 16 + l15] = acc[c][g];
}

// ---- kernel 3: rank-by-counting epilogue; wave = one row
__global__ __launch_bounds__(256)
void router_epilogue(const float* __restrict__ x,
                     const float* __restrict__ w_route,
                     const float* __restrict__ w_noise,
                     const float* __restrict__ noise,
                     const float* __restrict__ part,
                     float* __restrict__ out_probs,
                     float* __restrict__ out_idx)
{
    __shared__ float vals[4][64];
    __shared__ float srt[4][64];

    const int tid  = (int)threadIdx.x;
    const int lane = tid & 63;   // lane == expert index
    const int wid  = tid >> 6;
    const int grow = (int)blockIdx.x * 4 + wid;
    const float* p0 = part;
    const float* p1 = part + (size_t)NROWS * NOUT;

    const size_t ro = (size_t)grow * NOUT;
    const float route = p0[ro + lane] + p1[ro + lane];
    const float nz    = p0[ro + EDIM + lane] + p1[ro + EDIM + lane];
    const float nv    = noise[(size_t)grow * EDIM + lane];
    const float sp = fmaxf(nz, 0.f) + log1pf(expf(-fabsf(nz)));
    const float nl = route + nv * sp;

    vals[wid][lane] = nl;
    __syncthreads();

    // rank = #{j better than me}; "better" = (v_j > v_i) or tie with j < i
    int cnt = 0;
    #pragma unroll
    for (int jq = 0; jq < 16; ++jq) {
        const float4 v = *(const float4*)&vals[wid][jq * 4];
        const int j0 = jq * 4;
        cnt += (v.x > nl || (v.x == nl && (j0 + 0) < lane));
        cnt += (v.y > nl || (v.y == nl && (j0 + 1) < lane));
        cnt += (v.z > nl || (v.z == nl && (j0 + 2) < lane));
        cnt += (v.w > nl || (v.w == nl && (j0 + 3) < lane));
    }
    srt[wid][cnt] = nl;   // ranks are a permutation of 0..63
    __syncthreads();

    const float m = srt[wid][0];
    bool amb = false, flagme = false;
    float prev = m;
    #pragma unroll
    for (int t = 1; t <= TOPK; ++t) {
        const float vt = srt[wid][t];
        if (prev - vt < TAU) {
            amb = true;
            const float vb = 0.5f * (prev + vt);
            flagme = flagme || (fabsf(nl - vb) <= TAU);
        }
        prev = vt;
    }

    if (cnt < TOPK) out_idx[(size_t)grow * TOPK + cnt] = (float)lane;
    float ev = (cnt < TOPK) ? expf(nl - m) : 0.f;
    float s  = ev;
    #pragma unroll
    for (int off = 32; off >= 1; off >>= 1) s += __shfl_xor(s, off, 64);
    out_probs[(size_t)grow * EDIM + lane] = ev / s;

    if (amb) {
        // selective f64 repair: exact dots only for flagged experts
        unsigned long long mask = __ballot(flagme);
        double nld = (double)nl;
        const float* xr = x + (size_t)grow * CDIM;
        while (mask) {
            const int e = (int)__ffsll(mask) - 1;
            mask &= (mask - 1);
            double ar = 0.0, an = 0.0;
            const float* wrp = w_route + (size_t)e * CDIM;
            const float* wnp = w_noise + (size_t)e * CDIM;
            #pragma unroll
            for (int j = 0; j < 8; ++j) {
                const int k = (j * 64 + lane) * 4;   // coalesced
                const float4 xv = *(const float4*)(xr + k);
                const float4 rv = *(const float4*)(wrp + k);
                const float4 nq = *(const float4*)(wnp + k);
                ar = fma((double)xv.x, (double)rv.x, ar);
                ar = fma((double)xv.y, (double)rv.y, ar);
                ar = fma((double)xv.z, (double)rv.z, ar);
                ar = fma((double)xv.w, (double)rv.w, ar);
                an = fma((double)xv.x, (double)nq.x, an);
                an = fma((double)xv.y, (double)nq.y, an);
                an = fma((double)xv.z, (double)nq.z, an);
                an = fma((double)xv.w, (double)nq.w, an);
            }
            #pragma unroll
            for (int off = 32; off >= 1; off >>= 1) {
                ar += __shfl_xor(ar, off, 64);
                an += __shfl_xor(an, off, 64);
            }
            const double spd = fmax(an, 0.0) + log1p(exp(-fabs(an)));
            const double nve = (double)__shfl(nv, e, 64);
            const double v   = ar + nve * spd;
            if (lane == e) nld = v;
        }
        double workd = nld;
        int    rank2 = -1;
        double m2 = 0.0;
        #pragma unroll
        for (int t = 0; t < TOPK; ++t) {
            double bv = workd;
            int    bi = lane;
            #pragma unroll
            for (int off = 32; off >= 1; off >>= 1) {
                const double ov = __shfl_xor(bv, off, 64);
                const int    oi = __shfl_xor(bi, off, 64);
                if (ov > bv || (ov == bv && oi < bi)) { bv = ov; bi = oi; }
            }
            if (t == 0) m2 = bv;
            if (lane == bi) {
                rank2 = t;
                workd = -INFINITY;
                out_idx[(size_t)grow * TOPK + t] = (float)lane;
            }
        }
        float ev2 = (rank2 >= 0) ? expf((float)(nld - m2)) : 0.f;
        float s2  = ev2;
        #pragma unroll
        for (int off = 32; off >= 1; off >>= 1) s2 += __shfl_xor(s2, off, 64);
        out_probs[(size_t)grow * EDIM + lane] = ev2 / s2;
    }
}

extern "C" void kernel_launch(void* const* d_in, const int* in_sizes, int n_in,
                              void* d_out, int out_size, void* d_ws, size_t ws_size,
                              hipStream_t stream)
{
    const float* x       = (const float*)d_in[0];
    const float* w_route = (const float*)d_in[1];
    const float* w_noise = (const float*)d_in[2];
    const float* noise   = (const float*)d_in[3];

    const int n_rows = in_sizes[0] / CDIM;                 // 16384
    float* out_probs = (float*)d_out;                      // (B,T,E) fp32
    float* out_idx   = out_probs + (size_t)n_rows * EDIM;  // (B,T,K) as fp32

    short* whi  = (short*)d_ws;                            // 512 KB packed hi
    short* wlo  = whi + (size_t)NOUT * CDIM;               // 512 KB packed lo
    float* part = (float*)((char*)d_ws + 2u * 1024u * 1024u); // 2 x 16384 x 128 f32

    hipLaunchKernelGGL(convert_w, dim3(NOUT * CDIM / (256 * 8)), dim3(256), 0, stream,
                       w_route, w_noise, whi, wlo);
    hipLaunchKernelGGL(router_gemm, dim3((n_rows / BM) * 2), dim3(256), 0, stream,
                       x, whi, wlo, part);
    hipLaunchKernelGGL(router_epilogue, dim3(n_rows / 4), dim3(256), 0, stream,
                       x, w_route, w_noise, noise, part, out_probs, out_idx);
}